// Round 23
// baseline (562.729 us; speedup 1.0000x reference)
//
#include <hip/hip_runtime.h>
#include <hip/hip_fp16.h>
#include <math.h>

#define NN 20000
#define NNP 20224   // padded to 158*128 (= 316*64)
#define NGRP3 316   // NNP/64
#define NE 320000
#define D 50
#define TOWERS 5
#define TD 250      // TOWERS*D
#define ASTR 256    // padded row stride for ai/aj (halves)
#define FOUT 10
#define EPS 1e-5f

// BN+ReLU applied inline by readers of the layer state (k_bnapply removed).
__device__ __forceinline__ float bn_apply(float raw, int c,
                                          const float* __restrict__ bnv,
                                          const float* __restrict__ gam,
                                          const float* __restrict__ bet, int relu) {
    float mean = bnv[c] * (1.0f / NN);
    float var = bnv[50 + c] * (1.0f / NN) - mean * mean;
    float v = gam[c] * (raw - mean) * rsqrtf(var + EPS) + bet[c];
    return relu ? fmaxf(v, 0.f) : v;
}

// ------------------------------------------------------------------ setup
__global__ void k_deg(const int* __restrict__ dst, int* __restrict__ deg) {
    int e = blockIdx.x * 256 + threadIdx.x;
    if (e < NE) atomicAdd(&deg[dst[e]], 1);
}

__global__ __launch_bounds__(256) void k_hist(const int* __restrict__ deg,
                                              int* __restrict__ hist) {
    __shared__ int lh[256];
    int tid = threadIdx.x;
    lh[tid] = 0;
    __syncthreads();
    int n = blockIdx.x * 256 + tid;
    if (n < NN) atomicAdd(&lh[min(deg[n], 255)], 1);
    __syncthreads();
    if (lh[tid] > 0) atomicAdd(&hist[tid], lh[tid]);
}

// bin scans + avg_log + identity-BN constants for layer 0.
__global__ void k_binscan(const int* __restrict__ hist, int* __restrict__ binbase,
                          int* __restrict__ ebase, float* __restrict__ avglog_out,
                          float* __restrict__ bnid, float* __restrict__ gbid) {
    __shared__ int b[256];
    __shared__ int eb[256];
    __shared__ float lg[256];
    int tid = threadIdx.x;
    int h = hist[tid];
    b[tid] = h;
    eb[tid] = h * tid;
    lg[tid] = (float)h * logf((float)tid + 1.0f);
    __syncthreads();
    for (int off = 1; off < 256; off <<= 1) {
        int t1 = (tid >= off) ? b[tid - off] : 0;
        int t2 = (tid >= off) ? eb[tid - off] : 0;
        float t3 = (tid >= off) ? lg[tid - off] : 0.f;
        __syncthreads();
        b[tid] += t1; eb[tid] += t2; lg[tid] += t3;
        __syncthreads();
    }
    binbase[tid] = b[tid] - h;
    ebase[tid] = eb[tid] - h * tid;
    if (tid == 255) avglog_out[0] = lg[255];
    if (tid < 50)       { bnid[tid] = 0.f;        gbid[tid] = 1.f; }
    else if (tid < 100) { bnid[tid] = (float)NN;  gbid[tid] = 0.f; }
}

// LDS-histogram scatter + closed-form offs.
__global__ __launch_bounds__(256) void k_scatter(
    const int* __restrict__ deg, const int* __restrict__ binbase,
    const int* __restrict__ ebase, int* __restrict__ cursorb,
    int* __restrict__ perm, int* __restrict__ invp, int* __restrict__ offs) {
    __shared__ int lh[256];
    __shared__ int lbase[256];
    int tid = threadIdx.x;
    lh[tid] = 0;
    __syncthreads();
    int n = blockIdx.x * 256 + tid;
    int d = 0, slot = 0;
    bool ok = n < NN;
    if (ok) {
        d = min(deg[n], 255);
        slot = atomicAdd(&lh[d], 1);
    }
    __syncthreads();
    if (lh[tid] > 0) lbase[tid] = atomicAdd(&cursorb[tid], lh[tid]);
    __syncthreads();
    if (ok) {
        int r = binbase[d] + lbase[d] + slot;
        perm[r] = n;
        invp[n] = r;
        offs[r] = ebase[d] + (r - binbase[d]) * d;
    }
    if (n == 0) offs[NN] = NE;
}

__global__ void k_csr(const int* __restrict__ src, const int* __restrict__ dst,
                      const int* __restrict__ offs, const int* __restrict__ invp,
                      int* __restrict__ cursor, int* __restrict__ csr_src) {
    int e = blockIdx.x * 256 + threadIdx.x;
    if (e < NE) {
        int rd = invp[dst[e]];
        int slot = atomicAdd(&cursor[rd], 1);
        csr_src[offs[rd] + slot] = invp[src[e]];
    }
}

// embedding -> hrawT (feature-major, RANK space), zero pad columns
__global__ void k_emb(const int* __restrict__ x, const float* __restrict__ emb,
                      const int* __restrict__ perm, float* __restrict__ hrawT) {
    int idx = blockIdx.x * 256 + threadIdx.x;
    if (idx < D * NNP) {
        int c = idx / NNP, r = idx % NNP;
        hrawT[idx] = (r < NN) ? emb[x[perm[r]] * D + c] : 0.f;
    }
}

__global__ void k_wt(const float* __restrict__ postW, float* __restrict__ wT,
                     float* __restrict__ wxT) {
    int idx = blockIdx.x * 256 + threadIdx.x;
    const int WTN = 4 * TOWERS * 200 * 32;
    if (idx < WTN) {
        int l = idx / (TOWERS * 200 * 32);
        int r = idx % (TOWERS * 200 * 32);
        int t = r / (200 * 32); r %= 200 * 32;
        int j = r / 32, c = r % 32;
        float v = 0.f;
        if (c < 30) {
            int p = c / 10, g = c % 10;
            v = postW[l * 32500 + (t * FOUT + g) * 650 + 50 + p * 200 + j];
        }
        wT[idx] = v;
    } else if (idx < WTN + 4 * TOWERS * 50 * 16) {
        int k = idx - WTN;
        int l = k / (TOWERS * 50 * 16);
        int r = k % (TOWERS * 50 * 16);
        int t = r / (50 * 16); r %= 50 * 16;
        int j = r / 16, c = r % 16;
        float v = 0.f;
        if (c < 10) v = postW[l * 32500 + (t * FOUT + c) * 650 + j];
        wxT[k] = v;
    }
}

// ------------------------------------------------------------- per layer
// pre-NN: tid<256 -> ai column, tid>=256 -> aj column (fp16). BN+ReLU of the
// previous layer applied inline during x staging.
#define PRE_NT 16
__global__ __launch_bounds__(512) void k_pre(const float* __restrict__ hraw,
                                             const float* __restrict__ bnv,
                                             const float* __restrict__ gam,
                                             const float* __restrict__ bet, int relu,
                                             const float* __restrict__ preW, // [TD][2D]
                                             __half* __restrict__ aih,
                                             __half* __restrict__ ajh) {
    __shared__ float xl[PRE_NT * 52];
    int n0 = blockIdx.x * PRE_NT;
    int tid = threadIdx.x;
    for (int k = tid; k < PRE_NT * 52; k += 512) {
        int nl = k & 15, f = k >> 4;
        float v = 0.f;
        if (f < 50)
            v = bn_apply(hraw[(size_t)f * NNP + n0 + nl], f, bnv, gam, bet, relu);
        xl[nl * 52 + f] = v;
    }
    __syncthreads();
    int isj = tid >> 8;            // 0 = ai, 1 = aj
    int oo = tid & 255;            // column within the 256-half row
    __half* dstp = isj ? ajh : aih;
    if (oo < 250) {
        const float* w0 = preW + oo * 100 + isj * 50;
        float w[52];
#pragma unroll
        for (int f = 0; f < 50; ++f) w[f] = w0[f];
        w[50] = 0.f; w[51] = 0.f;
        for (int nl = 0; nl < PRE_NT; ++nl) {
            const float4* xv = (const float4*)&xl[nl * 52];
            float a0 = 0.f, a1 = 0.f, a2 = 0.f, a3 = 0.f;
#pragma unroll
            for (int j = 0; j < 12; j += 4) {
                float4 xa = xv[j], xb = xv[j + 1], xc = xv[j + 2], xd = xv[j + 3];
                a0 = fmaf(xa.x, w[4*j],   a0); a0 = fmaf(xa.y, w[4*j+1], a0);
                a0 = fmaf(xa.z, w[4*j+2], a0); a0 = fmaf(xa.w, w[4*j+3], a0);
                a1 = fmaf(xb.x, w[4*j+4], a1); a1 = fmaf(xb.y, w[4*j+5], a1);
                a1 = fmaf(xb.z, w[4*j+6], a1); a1 = fmaf(xb.w, w[4*j+7], a1);
                a2 = fmaf(xc.x, w[4*j+8], a2); a2 = fmaf(xc.y, w[4*j+9], a2);
                a2 = fmaf(xc.z, w[4*j+10], a2); a2 = fmaf(xc.w, w[4*j+11], a2);
                a3 = fmaf(xd.x, w[4*j+12], a3); a3 = fmaf(xd.y, w[4*j+13], a3);
                a3 = fmaf(xd.z, w[4*j+14], a3); a3 = fmaf(xd.w, w[4*j+15], a3);
            }
            float4 xe = xv[12];
            a0 = fmaf(xe.x, w[48], a0); a1 = fmaf(xe.y, w[49], a1);
            a2 = fmaf(xe.z, w[50], a2); a3 = fmaf(xe.w, w[51], a3);
            float a = (a0 + a1) + (a2 + a3);
            dstp[(size_t)(n0 + nl) * ASTR + oo] = __float2half(a);
        }
    } else {                       // pad columns 250..255 -> zeros
        for (int nl = 0; nl < PRE_NT; ++nl)
            dstp[(size_t)(n0 + nl) * ASTR + oo] = __float2half(0.f);
    }
}

#define ACCH(rawv) do { \
    const __half2* hp_ = (const __half2*)&(rawv); \
    _Pragma("unroll") \
    for (int j_ = 0; j_ < 4; ++j_) { \
        float2 f_ = __half22float2(hp_[j_]); \
        s1[2*j_]   += f_.x; s2[2*j_]   = fmaf(f_.x, f_.x, s2[2*j_]); \
        mn[2*j_]   = fminf(mn[2*j_], f_.x); mx[2*j_]   = fmaxf(mx[2*j_], f_.x); \
        s1[2*j_+1] += f_.y; s2[2*j_+1] = fmaf(f_.y, f_.y, s2[2*j_+1]); \
        mn[2*j_+1] = fminf(mn[2*j_+1], f_.y); mx[2*j_+1] = fmaxf(mx[2*j_+1], f_.y); \
    } \
} while (0)

// Edge aggregation: 4 instances per node. Wave = 8 nodes x 8 lanes; lane
// loads float4 = 8 halves (16 B). Grid = 313 nodeblocks x 4 chunks; nb
// reversed for tail packing. 4-way unroll with csr software pipeline.
__global__ __launch_bounds__(512) void k_agg(
    const __half* __restrict__ aj, const int* __restrict__ offs,
    const int* __restrict__ csr_src, const __half* __restrict__ ai,
    const float* __restrict__ preB, __half* __restrict__ aggT) {
    int chunk = blockIdx.x & 3;
    int nb = (gridDim.x >> 2) - 1 - (blockIdx.x >> 2);   // reversed
    int tid = threadIdx.x;
    int wave = tid >> 6, lane = tid & 63;
    int g = lane >> 3, q = lane & 7;
    int r = nb * 64 + wave * 8 + g;
    int coloff = chunk * 8 + q;            // float4 (8-half) column, 0..31
    bool ok = r < NN;
    int e0 = 0, dg = 0;
    if (ok) { e0 = offs[r]; dg = offs[r + 1] - e0; }
    int mdeg = dg;
#pragma unroll
    for (int o = 8; o < 64; o <<= 1) mdeg = min(mdeg, __shfl_xor(mdeg, o));

    const float4* ajv = (const float4*)aj;   // row = 32 x 16 B
    float s1[8], s2[8], mn[8], mx[8];
#pragma unroll
    for (int k = 0; k < 8; ++k) {
        s1[k] = 0.f; s2[k] = 0.f; mn[k] = INFINITY; mx[k] = -INFINITY;
    }

    int nblk = mdeg >> 2;
    int spref[4];
    if (nblk > 0) {
#pragma unroll
        for (int k = 0; k < 4; ++k) spref[k] = csr_src[e0 + k];
    }
    for (int b = 0; b < nblk; ++b) {
        int scur[4];
#pragma unroll
        for (int k = 0; k < 4; ++k) scur[k] = spref[k];
        int nxt = (b + 1 < nblk) ? (b + 1) * 4 : 0;   // prefetch next block
#pragma unroll
        for (int k = 0; k < 4; ++k) spref[k] = csr_src[e0 + nxt + k];
        float4 raw[4];
#pragma unroll
        for (int k = 0; k < 4; ++k)
            raw[k] = ajv[((unsigned)scur[k] << 5) + coloff];
#pragma unroll
        for (int k = 0; k < 4; ++k) ACCH(raw[k]);
    }
    int it = nblk << 2;
    for (; it < mdeg; ++it) {
        float4 raw = ajv[((unsigned)csr_src[e0 + it] << 5) + coloff];
        ACCH(raw);
    }
    while (__any(it < dg)) {                  // tiny tail (bin boundaries)
        bool valid = it < dg;
        float4 raw = ajv[((unsigned)csr_src[valid ? e0 + it : e0] << 5) + coloff];
        const __half2* hp = (const __half2*)&raw;
#pragma unroll
        for (int j = 0; j < 4; ++j) {
            float2 f = __half22float2(hp[j]);
            float vx = valid ? f.x : 0.f, vy = valid ? f.y : 0.f;
            s1[2*j]   += vx; s2[2*j]   = fmaf(vx, vx, s2[2*j]);
            mn[2*j]   = fminf(mn[2*j], valid ? f.x : INFINITY);
            mx[2*j]   = fmaxf(mx[2*j], valid ? f.x : -INFINITY);
            s1[2*j+1] += vy; s2[2*j+1] = fmaf(vy, vy, s2[2*j+1]);
            mn[2*j+1] = fminf(mn[2*j+1], valid ? f.y : INFINITY);
            mx[2*j+1] = fmaxf(mx[2*j+1], valid ? f.y : -INFINITY);
        }
        ++it;
    }

    if (ok) {
        float inv = 1.0f / (float)max(dg, 1);
        float4 aihr = ((const float4*)ai)[(size_t)r * 32 + coloff];
        const __half2* ap = (const __half2*)&aihr;
        int f0 = coloff * 8;
#pragma unroll
        for (int j = 0; j < 4; ++j) {
            float2 av = __half22float2(ap[j]);
            float aval[2] = {av.x, av.y};
#pragma unroll
            for (int h = 0; h < 2; ++h) {
                int k = 2 * j + h;
                int f = f0 + k;
                if (f < TD) {
                    float m1 = s1[k] * inv;
                    float sd = sqrtf(fmaxf(s2[k] * inv - m1 * m1, 0.f) + EPS);
                    float mm, mnv, mxv;
                    if (dg > 0) {
                        float base = aval[h] + preB[f];
                        mm = m1 + base; mnv = mn[k] + base; mxv = mx[k] + base;
                    } else {
                        mm = 0.f; mnv = 0.f; mxv = 0.f; sd = sqrtf(EPS);
                    }
                    int t = f / 50, gg = f - t * 50;
                    __half* col = aggT + (size_t)(t * 200 + gg) * NNP + r;
                    col[0]                 = __float2half(mm);
                    col[(size_t)50 * NNP]  = __float2half(mnv);
                    col[(size_t)100 * NNP] = __float2half(mxv);
                    col[(size_t)150 * NNP] = __float2half(sd);
                }
            }
        }
    }
}

// post-NN: 256 threads = 4 waves; wave qd handles j = qd*50..qd*50+49 with
// 10-deep explicit load batching. Wave 1 computes the x-part (with inline
// BN+ReLU of the previous layer); wave 0 combines.
__global__ __launch_bounds__(256) void k_post(
    const float* __restrict__ hraw, const float* __restrict__ bnv,
    const float* __restrict__ gam, const float* __restrict__ bet, int relu,
    const __half* __restrict__ aggT, const int* __restrict__ offs,
    const float* __restrict__ wT,    // [T][200][32]
    const float* __restrict__ wxT,   // [T][50][16]
    const float* __restrict__ postB, // [50]
    const float* __restrict__ avg_accum, float* __restrict__ yT) {
    __shared__ float dp[3][64][33];
    __shared__ float xs[64][11];
    int t = blockIdx.x / NGRP3;
    int grp = blockIdx.x - t * NGRP3;
    int tid = threadIdx.x;
    int qd = tid >> 6, ln = tid & 63;
    int qdu = __builtin_amdgcn_readfirstlane(qd);
    int n = grp * 64 + ln;

    float acc[30];
#pragma unroll
    for (int i = 0; i < 30; ++i) acc[i] = 0.f;
    const __half* aggcol = aggT + (size_t)(t * 200) * NNP + n;
    const float4* wv = (const float4*)(wT + t * 200 * 32);
    int j0 = qdu * 50;
    for (int b = 0; b < 5; ++b) {
        float av[10];
#pragma unroll
        for (int k = 0; k < 10; ++k)
            av[k] = __half2float(aggcol[(size_t)(j0 + b * 10 + k) * NNP]);
#pragma unroll
        for (int k = 0; k < 10; ++k) {
            int j = j0 + b * 10 + k;
            float a = av[k];
            float4 w0 = wv[j * 8 + 0], w1 = wv[j * 8 + 1], w2 = wv[j * 8 + 2],
                   w3 = wv[j * 8 + 3], w4 = wv[j * 8 + 4], w5 = wv[j * 8 + 5],
                   w6 = wv[j * 8 + 6], w7 = wv[j * 8 + 7];
            acc[0] = fmaf(a, w0.x, acc[0]);   acc[1] = fmaf(a, w0.y, acc[1]);
            acc[2] = fmaf(a, w0.z, acc[2]);   acc[3] = fmaf(a, w0.w, acc[3]);
            acc[4] = fmaf(a, w1.x, acc[4]);   acc[5] = fmaf(a, w1.y, acc[5]);
            acc[6] = fmaf(a, w1.z, acc[6]);   acc[7] = fmaf(a, w1.w, acc[7]);
            acc[8] = fmaf(a, w2.x, acc[8]);   acc[9] = fmaf(a, w2.y, acc[9]);
            acc[10] = fmaf(a, w2.z, acc[10]); acc[11] = fmaf(a, w2.w, acc[11]);
            acc[12] = fmaf(a, w3.x, acc[12]); acc[13] = fmaf(a, w3.y, acc[13]);
            acc[14] = fmaf(a, w3.z, acc[14]); acc[15] = fmaf(a, w3.w, acc[15]);
            acc[16] = fmaf(a, w4.x, acc[16]); acc[17] = fmaf(a, w4.y, acc[17]);
            acc[18] = fmaf(a, w4.z, acc[18]); acc[19] = fmaf(a, w4.w, acc[19]);
            acc[20] = fmaf(a, w5.x, acc[20]); acc[21] = fmaf(a, w5.y, acc[21]);
            acc[22] = fmaf(a, w5.z, acc[22]); acc[23] = fmaf(a, w5.w, acc[23]);
            acc[24] = fmaf(a, w6.x, acc[24]); acc[25] = fmaf(a, w6.y, acc[25]);
            acc[26] = fmaf(a, w6.z, acc[26]); acc[27] = fmaf(a, w6.w, acc[27]);
            acc[28] = fmaf(a, w7.x, acc[28]); acc[29] = fmaf(a, w7.y, acc[29]);
        }
    }
    if (qdu == 1) {                 // x-part on wave 1, batched, inline BN
        float xacc[10];
#pragma unroll
        for (int i = 0; i < 10; ++i) xacc[i] = 0.f;
        const float4* wxv = (const float4*)(wxT + t * 50 * 16);
        for (int b = 0; b < 5; ++b) {
            float av[10];
#pragma unroll
            for (int k = 0; k < 10; ++k) {
                int j = b * 10 + k;
                av[k] = bn_apply(hraw[(size_t)j * NNP + n], j, bnv, gam, bet, relu);
            }
#pragma unroll
            for (int k = 0; k < 10; ++k) {
                int j = b * 10 + k;
                float a = av[k];
                float4 x0 = wxv[j * 4 + 0], x1 = wxv[j * 4 + 1], x2 = wxv[j * 4 + 2];
                xacc[0] = fmaf(a, x0.x, xacc[0]); xacc[1] = fmaf(a, x0.y, xacc[1]);
                xacc[2] = fmaf(a, x0.z, xacc[2]); xacc[3] = fmaf(a, x0.w, xacc[3]);
                xacc[4] = fmaf(a, x1.x, xacc[4]); xacc[5] = fmaf(a, x1.y, xacc[5]);
                xacc[6] = fmaf(a, x1.z, xacc[6]); xacc[7] = fmaf(a, x1.w, xacc[7]);
                xacc[8] = fmaf(a, x2.x, xacc[8]); xacc[9] = fmaf(a, x2.y, xacc[9]);
            }
        }
#pragma unroll
        for (int g = 0; g < 10; ++g) xs[ln][g] = xacc[g];
    }
    if (qdu != 0) {
#pragma unroll
        for (int g = 0; g < 30; ++g) dp[qdu - 1][ln][g] = acc[g];
    }
    __syncthreads();
    if (qd == 0 && n < NN) {
        int dgn = offs[n + 1] - offs[n];
        float cnt = (float)max(dgn, 1);
        float sc = logf(cnt + 1.0f) / (avg_accum[0] * (1.0f / NN));
        float isc = 1.0f / sc;
#pragma unroll
        for (int g = 0; g < 10; ++g) {
            float a0 = acc[g]      + dp[0][ln][g]      + dp[1][ln][g]      + dp[2][ln][g];
            float a1 = acc[10 + g] + dp[0][ln][10 + g] + dp[1][ln][10 + g] + dp[2][ln][10 + g];
            float a2 = acc[20 + g] + dp[0][ln][20 + g] + dp[1][ln][20 + g] + dp[2][ln][20 + g];
            yT[(size_t)(t * FOUT + g) * NNP + n] =
                postB[t * FOUT + g] + xs[ln][g] + a0 + sc * a1 + isc * a2;
        }
    }
}

// 50x50 linear + BN partial stats. 316 blocks x 256 thr. Writes hrawT.
__global__ __launch_bounds__(256) void k_lin(
    const float* __restrict__ yT, const float* __restrict__ linW,
    const float* __restrict__ linB, float* __restrict__ hrawT,
    float* __restrict__ part) {
    __shared__ float yl[64][51];
    __shared__ float bs[100];
    int tid = threadIdx.x;
    int n0 = blockIdx.x * 64;
    for (int idx = tid; idx < 64 * 50; idx += 256) {
        int q = idx >> 6, nl = idx & 63;
        yl[nl][q] = yT[(size_t)q * NNP + n0 + nl];
    }
    __syncthreads();
    int w = tid >> 6, nl = tid & 63;
    int wu = __builtin_amdgcn_readfirstlane(w);
    int n = n0 + nl;
    bool ok = n < NN;
    int c0 = wu * 13, c1 = min(50, c0 + 13);
    for (int c = c0; c < c1; ++c) {
        const float* wr = linW + c * 50;
        float a = linB[c];
#pragma unroll
        for (int q = 0; q < 50; ++q) a = fmaf(wr[q], yl[nl][q], a);
        hrawT[(size_t)c * NNP + n] = a;
        float s = ok ? a : 0.f;
        float sq = s * s;
#pragma unroll
        for (int o = 32; o > 0; o >>= 1) {
            s += __shfl_down(s, o);
            sq += __shfl_down(sq, o);
        }
        if (nl == 0) { bs[c] = s; bs[50 + c] = sq; }
    }
    __syncthreads();
    if (tid < 100) part[blockIdx.x * 100 + tid] = bs[tid];
}

// reduce part[316][100] -> bn[100].
__global__ __launch_bounds__(256) void k_bnred(const float* __restrict__ part,
                                               float* __restrict__ bn) {
    int c = blockIdx.x;
    int tid = threadIdx.x;
    float s = 0.f;
    for (int b = tid; b < NGRP3; b += 256) s += part[b * 100 + c];
    for (int o = 32; o > 0; o >>= 1) s += __shfl_down(s, o);
    __shared__ float ws[4];
    int lane = tid & 63, w = tid >> 6;
    if (lane == 0) ws[w] = s;
    __syncthreads();
    if (tid == 0) bn[c] = ws[0] + ws[1] + ws[2] + ws[3];
}

__global__ void k_mlp(const float* __restrict__ hraw, const float* __restrict__ bnv,
                      const float* __restrict__ gam, const float* __restrict__ bet,
                      const int* __restrict__ perm,
                      const float* __restrict__ W1, const float* __restrict__ b1,
                      const float* __restrict__ W2, const float* __restrict__ b2,
                      float* __restrict__ out) {
    int n = blockIdx.x * 256 + threadIdx.x;
    if (n >= NN) return;
    float hv[50];
#pragma unroll
    for (int f = 0; f < 50; ++f)
        hv[f] = bn_apply(hraw[(size_t)f * NNP + n], f, bnv, gam, bet, 1);
    float s = b2[0];
    for (int o = 0; o < 25; ++o) {
        float a = b1[o];
        const float* w = W1 + o * 50;
#pragma unroll
        for (int f = 0; f < 50; ++f) a += w[f] * hv[f];
        s += W2[o] * fmaxf(a, 0.f);
    }
    out[perm[n]] = 1.0f / (1.0f + expf(-s));
}

// ------------------------------------------------------------------ launch
extern "C" void kernel_launch(void* const* d_in, const int* in_sizes, int n_in,
                              void* d_out, int out_size, void* d_ws, size_t ws_size,
                              hipStream_t stream) {
    const int* x = (const int*)d_in[0];
    const int* ei = (const int*)d_in[1];
    const int* src = ei;
    const int* dst = ei + NE;
    const float* emb   = (const float*)d_in[4];
    const float* preW  = (const float*)d_in[5];
    const float* preB  = (const float*)d_in[6];
    const float* postW = (const float*)d_in[7];
    const float* postB = (const float*)d_in[8];
    const float* linW  = (const float*)d_in[9];
    const float* linB  = (const float*)d_in[10];
    const float* gamma = (const float*)d_in[11];
    const float* beta  = (const float*)d_in[12];
    const float* W1 = (const float*)d_in[13];
    const float* b1 = (const float*)d_in[14];
    const float* W2 = (const float*)d_in[15];
    const float* b2 = (const float*)d_in[16];
    float* outp = (float*)d_out;

    char* wsp = (char*)d_ws;
    size_t off = 0;
    auto alloc = [&](size_t bytes) {
        void* p = wsp + off;
        off = (off + bytes + 1023) & ~(size_t)1023;
        return p;
    };
    int* deg     = (int*)alloc(NN * 4);
    int* cursor  = (int*)alloc(NN * 4);
    int* offs    = (int*)alloc((NN + 1) * 4);
    int* csr     = (int*)alloc(NE * 4);
    int* perm    = (int*)alloc(NN * 4);
    int* invp    = (int*)alloc(NN * 4);
    int* hist    = (int*)alloc(256 * 4);
    int* binbase = (int*)alloc(256 * 4);
    int* ebase   = (int*)alloc(256 * 4);
    int* cursorb = (int*)alloc(256 * 4);
    float* bn    = (float*)alloc(512);     // [0:100) BN stats, [100] avg_log
    float* bnid  = (float*)alloc(512);     // identity BN for layer 0
    float* gbid  = (float*)alloc(512);     // identity gamma(0:50)/beta(50:100)
    float* part  = (float*)alloc((size_t)NGRP3 * 100 * 4);
    float* hrawT = (float*)alloc((size_t)D * NNP * 4);
    float* yT    = (float*)alloc((size_t)D * NNP * 4);
    __half* aih  = (__half*)alloc((size_t)NN * ASTR * 2);
    __half* ajh  = (__half*)alloc((size_t)NN * ASTR * 2);
    float* wT    = (float*)alloc((size_t)4 * TOWERS * 200 * 32 * 4);
    float* wxT   = (float*)alloc((size_t)4 * TOWERS * 50 * 16 * 4);
    __half* aggT = (__half*)alloc((size_t)1000 * NNP * 2);  // fp16 stats+base
    (void)ws_size; (void)in_sizes; (void)n_in; (void)out_size;

    hipMemsetAsync(deg, 0, NN * 4, stream);
    hipMemsetAsync(cursor, 0, NN * 4, stream);
    hipMemsetAsync(hist, 0, 256 * 4, stream);
    hipMemsetAsync(cursorb, 0, 256 * 4, stream);
    hipMemsetAsync(bn, 0, 512, stream);

    k_deg<<<(NE + 255) / 256, 256, 0, stream>>>(dst, deg);
    k_hist<<<(NN + 255) / 256, 256, 0, stream>>>(deg, hist);
    k_binscan<<<1, 256, 0, stream>>>(hist, binbase, ebase, bn + 100, bnid, gbid);
    k_scatter<<<(NN + 255) / 256, 256, 0, stream>>>(deg, binbase, ebase, cursorb,
                                                    perm, invp, offs);
    k_csr<<<(NE + 255) / 256, 256, 0, stream>>>(src, dst, offs, invp, cursor, csr);
    k_emb<<<(D * NNP + 255) / 256, 256, 0, stream>>>(x, emb, perm, hrawT);
    k_wt<<<(4 * TOWERS * 200 * 32 + 4 * TOWERS * 50 * 16 + 255) / 256, 256, 0, stream>>>(postW, wT, wxT);

    int aggblocks = 313 * 4;
    for (int l = 0; l < 4; ++l) {
        const float* bnu = (l == 0) ? bnid : bn;
        const float* gu  = (l == 0) ? gbid : gamma + (l - 1) * 50;
        const float* bu  = (l == 0) ? gbid + 50 : beta + (l - 1) * 50;
        int relu = (l > 0) ? 1 : 0;
        k_pre<<<NN / PRE_NT, 512, 0, stream>>>(hrawT, bnu, gu, bu, relu,
                                               preW + l * TD * 100, aih, ajh);
        k_agg<<<aggblocks, 512, 0, stream>>>(ajh, offs, csr, aih, preB + l * TD, aggT);
        k_post<<<NGRP3 * TOWERS, 256, 0, stream>>>(hrawT, bnu, gu, bu, relu,
                                                   aggT, offs,
                                                   wT + l * TOWERS * 200 * 32,
                                                   wxT + l * TOWERS * 50 * 16,
                                                   postB + l * 50, bn + 100, yT);
        k_lin<<<NGRP3, 256, 0, stream>>>(yT, linW + l * 2500, linB + l * 50, hrawT, part);
        k_bnred<<<100, 256, 0, stream>>>(part, bn);
    }
    k_mlp<<<(NN + 255) / 256, 256, 0, stream>>>(hrawT, bn, gamma + 150, beta + 150,
                                                perm, W1, b1, W2, b2, outp);
}

// Round 24
// 550.993 us; speedup vs baseline: 1.0213x; 1.0213x over previous
//
#include <hip/hip_runtime.h>
#include <hip/hip_fp16.h>
#include <math.h>

#define NN 20000
#define NNP 20224   // padded to 158*128 (= 316*64)
#define NGRP3 316   // NNP/64
#define NE 320000
#define D 50
#define TOWERS 5
#define TD 250      // TOWERS*D
#define ASTR 256    // padded row stride for ai/aj (halves)
#define FOUT 10
#define EPS 1e-5f

// ------------------------------------------------------------------ setup
__global__ void k_deg(const int* __restrict__ dst, int* __restrict__ deg) {
    int e = blockIdx.x * 256 + threadIdx.x;
    if (e < NE) atomicAdd(&deg[dst[e]], 1);
}

__global__ __launch_bounds__(256) void k_hist(const int* __restrict__ deg,
                                              int* __restrict__ hist) {
    __shared__ int lh[256];
    int tid = threadIdx.x;
    lh[tid] = 0;
    __syncthreads();
    int n = blockIdx.x * 256 + tid;
    if (n < NN) atomicAdd(&lh[min(deg[n], 255)], 1);
    __syncthreads();
    if (lh[tid] > 0) atomicAdd(&hist[tid], lh[tid]);
}

__global__ void k_binscan(const int* __restrict__ hist, int* __restrict__ binbase,
                          int* __restrict__ ebase, float* __restrict__ avglog_out) {
    __shared__ int b[256];
    __shared__ int eb[256];
    __shared__ float lg[256];
    int tid = threadIdx.x;
    int h = hist[tid];
    b[tid] = h;
    eb[tid] = h * tid;
    lg[tid] = (float)h * logf((float)tid + 1.0f);
    __syncthreads();
    for (int off = 1; off < 256; off <<= 1) {
        int t1 = (tid >= off) ? b[tid - off] : 0;
        int t2 = (tid >= off) ? eb[tid - off] : 0;
        float t3 = (tid >= off) ? lg[tid - off] : 0.f;
        __syncthreads();
        b[tid] += t1; eb[tid] += t2; lg[tid] += t3;
        __syncthreads();
    }
    binbase[tid] = b[tid] - h;
    ebase[tid] = eb[tid] - h * tid;
    if (tid == 255) avglog_out[0] = lg[255];
}

// LDS-histogram scatter + closed-form offs.
__global__ __launch_bounds__(256) void k_scatter(
    const int* __restrict__ deg, const int* __restrict__ binbase,
    const int* __restrict__ ebase, int* __restrict__ cursorb,
    int* __restrict__ perm, int* __restrict__ invp, int* __restrict__ offs) {
    __shared__ int lh[256];
    __shared__ int lbase[256];
    int tid = threadIdx.x;
    lh[tid] = 0;
    __syncthreads();
    int n = blockIdx.x * 256 + tid;
    int d = 0, slot = 0;
    bool ok = n < NN;
    if (ok) {
        d = min(deg[n], 255);
        slot = atomicAdd(&lh[d], 1);
    }
    __syncthreads();
    if (lh[tid] > 0) lbase[tid] = atomicAdd(&cursorb[tid], lh[tid]);
    __syncthreads();
    if (ok) {
        int r = binbase[d] + lbase[d] + slot;
        perm[r] = n;
        invp[n] = r;
        offs[r] = ebase[d] + (r - binbase[d]) * d;
    }
    if (n == 0) offs[NN] = NE;
}

__global__ void k_csr(const int* __restrict__ src, const int* __restrict__ dst,
                      const int* __restrict__ offs, const int* __restrict__ invp,
                      int* __restrict__ cursor, int* __restrict__ csr_src) {
    int e = blockIdx.x * 256 + threadIdx.x;
    if (e < NE) {
        int rd = invp[dst[e]];
        int slot = atomicAdd(&cursor[rd], 1);
        csr_src[offs[rd] + slot] = invp[src[e]];
    }
}

__global__ void k_emb(const int* __restrict__ x, const float* __restrict__ emb,
                      const int* __restrict__ perm, float* __restrict__ hT) {
    int idx = blockIdx.x * 256 + threadIdx.x;
    if (idx < D * NNP) {
        int c = idx / NNP, r = idx % NNP;
        hT[idx] = (r < NN) ? emb[x[perm[r]] * D + c] : 0.f;
    }
}

__global__ void k_wt(const float* __restrict__ postW, float* __restrict__ wT,
                     float* __restrict__ wxT) {
    int idx = blockIdx.x * 256 + threadIdx.x;
    const int WTN = 4 * TOWERS * 200 * 32;
    if (idx < WTN) {
        int l = idx / (TOWERS * 200 * 32);
        int r = idx % (TOWERS * 200 * 32);
        int t = r / (200 * 32); r %= 200 * 32;
        int j = r / 32, c = r % 32;
        float v = 0.f;
        if (c < 30) {
            int p = c / 10, g = c % 10;
            v = postW[l * 32500 + (t * FOUT + g) * 650 + 50 + p * 200 + j];
        }
        wT[idx] = v;
    } else if (idx < WTN + 4 * TOWERS * 50 * 16) {
        int k = idx - WTN;
        int l = k / (TOWERS * 50 * 16);
        int r = k % (TOWERS * 50 * 16);
        int t = r / (50 * 16); r %= 50 * 16;
        int j = r / 16, c = r % 16;
        float v = 0.f;
        if (c < 10) v = postW[l * 32500 + (t * FOUT + c) * 650 + j];
        wxT[k] = v;
    }
}

// ------------------------------------------------------------- per layer
// pre-NN: tid<256 -> ai column, tid>=256 -> aj column (fp16).
#define PRE_NT 16
__global__ __launch_bounds__(512) void k_pre(const float* __restrict__ hT,
                                             const float* __restrict__ preW, // [TD][2D]
                                             __half* __restrict__ aih,
                                             __half* __restrict__ ajh) {
    __shared__ float xl[PRE_NT * 52];
    int n0 = blockIdx.x * PRE_NT;
    int tid = threadIdx.x;
    for (int k = tid; k < PRE_NT * 52; k += 512) {
        int nl = k & 15, f = k >> 4;
        xl[nl * 52 + f] = (f < 50) ? hT[(size_t)f * NNP + n0 + nl] : 0.f;
    }
    __syncthreads();
    int isj = tid >> 8;            // 0 = ai, 1 = aj
    int oo = tid & 255;            // column within the 256-half row
    __half* dstp = isj ? ajh : aih;
    if (oo < 250) {
        const float* w0 = preW + oo * 100 + isj * 50;
        float w[52];
#pragma unroll
        for (int f = 0; f < 50; ++f) w[f] = w0[f];
        w[50] = 0.f; w[51] = 0.f;
        for (int nl = 0; nl < PRE_NT; ++nl) {
            const float4* xv = (const float4*)&xl[nl * 52];
            float a0 = 0.f, a1 = 0.f, a2 = 0.f, a3 = 0.f;
#pragma unroll
            for (int j = 0; j < 12; j += 4) {
                float4 xa = xv[j], xb = xv[j + 1], xc = xv[j + 2], xd = xv[j + 3];
                a0 = fmaf(xa.x, w[4*j],   a0); a0 = fmaf(xa.y, w[4*j+1], a0);
                a0 = fmaf(xa.z, w[4*j+2], a0); a0 = fmaf(xa.w, w[4*j+3], a0);
                a1 = fmaf(xb.x, w[4*j+4], a1); a1 = fmaf(xb.y, w[4*j+5], a1);
                a1 = fmaf(xb.z, w[4*j+6], a1); a1 = fmaf(xb.w, w[4*j+7], a1);
                a2 = fmaf(xc.x, w[4*j+8], a2); a2 = fmaf(xc.y, w[4*j+9], a2);
                a2 = fmaf(xc.z, w[4*j+10], a2); a2 = fmaf(xc.w, w[4*j+11], a2);
                a3 = fmaf(xd.x, w[4*j+12], a3); a3 = fmaf(xd.y, w[4*j+13], a3);
                a3 = fmaf(xd.z, w[4*j+14], a3); a3 = fmaf(xd.w, w[4*j+15], a3);
            }
            float4 xe = xv[12];
            a0 = fmaf(xe.x, w[48], a0); a1 = fmaf(xe.y, w[49], a1);
            a2 = fmaf(xe.z, w[50], a2); a3 = fmaf(xe.w, w[51], a3);
            float a = (a0 + a1) + (a2 + a3);
            dstp[(size_t)(n0 + nl) * ASTR + oo] = __float2half(a);
        }
    } else {                       // pad columns 250..255 -> zeros
        for (int nl = 0; nl < PRE_NT; ++nl)
            dstp[(size_t)(n0 + nl) * ASTR + oo] = __float2half(0.f);
    }
}

#define ACCH(rawv) do { \
    const __half2* hp_ = (const __half2*)&(rawv); \
    _Pragma("unroll") \
    for (int j_ = 0; j_ < 4; ++j_) { \
        float2 f_ = __half22float2(hp_[j_]); \
        s1[2*j_]   += f_.x; s2[2*j_]   = fmaf(f_.x, f_.x, s2[2*j_]); \
        mn[2*j_]   = fminf(mn[2*j_], f_.x); mx[2*j_]   = fmaxf(mx[2*j_], f_.x); \
        s1[2*j_+1] += f_.y; s2[2*j_+1] = fmaf(f_.y, f_.y, s2[2*j_+1]); \
        mn[2*j_+1] = fminf(mn[2*j_+1], f_.y); mx[2*j_+1] = fmaxf(mx[2*j_+1], f_.y); \
    } \
} while (0)

// Edge aggregation: 4 instances per node. Wave = 8 nodes x 8 lanes; lane
// loads float4 = 8 halves (16 B). Grid = 313 nodeblocks x 4 chunks; nb
// reversed for tail packing. 4-way unroll with csr software pipeline.
__global__ __launch_bounds__(512) void k_agg(
    const __half* __restrict__ aj, const int* __restrict__ offs,
    const int* __restrict__ csr_src, const __half* __restrict__ ai,
    const float* __restrict__ preB, __half* __restrict__ aggT) {
    int chunk = blockIdx.x & 3;
    int nb = (gridDim.x >> 2) - 1 - (blockIdx.x >> 2);   // reversed
    int tid = threadIdx.x;
    int wave = tid >> 6, lane = tid & 63;
    int g = lane >> 3, q = lane & 7;
    int r = nb * 64 + wave * 8 + g;
    int coloff = chunk * 8 + q;            // float4 (8-half) column, 0..31
    bool ok = r < NN;
    int e0 = 0, dg = 0;
    if (ok) { e0 = offs[r]; dg = offs[r + 1] - e0; }
    int mdeg = dg;
#pragma unroll
    for (int o = 8; o < 64; o <<= 1) mdeg = min(mdeg, __shfl_xor(mdeg, o));

    const float4* ajv = (const float4*)aj;   // row = 32 x 16 B
    float s1[8], s2[8], mn[8], mx[8];
#pragma unroll
    for (int k = 0; k < 8; ++k) {
        s1[k] = 0.f; s2[k] = 0.f; mn[k] = INFINITY; mx[k] = -INFINITY;
    }

    int nblk = mdeg >> 2;
    int spref[4];
    if (nblk > 0) {
#pragma unroll
        for (int k = 0; k < 4; ++k) spref[k] = csr_src[e0 + k];
    }
    for (int b = 0; b < nblk; ++b) {
        int scur[4];
#pragma unroll
        for (int k = 0; k < 4; ++k) scur[k] = spref[k];
        int nxt = (b + 1 < nblk) ? (b + 1) * 4 : 0;   // prefetch next block
#pragma unroll
        for (int k = 0; k < 4; ++k) spref[k] = csr_src[e0 + nxt + k];
        float4 raw[4];
#pragma unroll
        for (int k = 0; k < 4; ++k)
            raw[k] = ajv[((unsigned)scur[k] << 5) + coloff];
#pragma unroll
        for (int k = 0; k < 4; ++k) ACCH(raw[k]);
    }
    int it = nblk << 2;
    for (; it < mdeg; ++it) {
        float4 raw = ajv[((unsigned)csr_src[e0 + it] << 5) + coloff];
        ACCH(raw);
    }
    while (__any(it < dg)) {                  // tiny tail (bin boundaries)
        bool valid = it < dg;
        float4 raw = ajv[((unsigned)csr_src[valid ? e0 + it : e0] << 5) + coloff];
        const __half2* hp = (const __half2*)&raw;
#pragma unroll
        for (int j = 0; j < 4; ++j) {
            float2 f = __half22float2(hp[j]);
            float vx = valid ? f.x : 0.f, vy = valid ? f.y : 0.f;
            s1[2*j]   += vx; s2[2*j]   = fmaf(vx, vx, s2[2*j]);
            mn[2*j]   = fminf(mn[2*j], valid ? f.x : INFINITY);
            mx[2*j]   = fmaxf(mx[2*j], valid ? f.x : -INFINITY);
            s1[2*j+1] += vy; s2[2*j+1] = fmaf(vy, vy, s2[2*j+1]);
            mn[2*j+1] = fminf(mn[2*j+1], valid ? f.y : INFINITY);
            mx[2*j+1] = fmaxf(mx[2*j+1], valid ? f.y : -INFINITY);
        }
        ++it;
    }

    if (ok) {
        float inv = 1.0f / (float)max(dg, 1);
        float4 aihr = ((const float4*)ai)[(size_t)r * 32 + coloff];
        const __half2* ap = (const __half2*)&aihr;
        int f0 = coloff * 8;
#pragma unroll
        for (int j = 0; j < 4; ++j) {
            float2 av = __half22float2(ap[j]);
            float aval[2] = {av.x, av.y};
#pragma unroll
            for (int h = 0; h < 2; ++h) {
                int k = 2 * j + h;
                int f = f0 + k;
                if (f < TD) {
                    float m1 = s1[k] * inv;
                    float sd = sqrtf(fmaxf(s2[k] * inv - m1 * m1, 0.f) + EPS);
                    float mm, mnv, mxv;
                    if (dg > 0) {
                        float base = aval[h] + preB[f];
                        mm = m1 + base; mnv = mn[k] + base; mxv = mx[k] + base;
                    } else {
                        mm = 0.f; mnv = 0.f; mxv = 0.f; sd = sqrtf(EPS);
                    }
                    int t = f / 50, gg = f - t * 50;
                    __half* col = aggT + (size_t)(t * 200 + gg) * NNP + r;
                    col[0]                 = __float2half(mm);
                    col[(size_t)50 * NNP]  = __float2half(mnv);
                    col[(size_t)100 * NNP] = __float2half(mxv);
                    col[(size_t)150 * NNP] = __float2half(sd);
                }
            }
        }
    }
}

// post-NN: 256 threads = 4 waves; wave qd handles j = qd*50..qd*50+49 with
// 10-deep explicit load batching. Wave 1 computes the x-part; wave 0 combines.
__global__ __launch_bounds__(256) void k_post(
    const float* __restrict__ hT, const __half* __restrict__ aggT,
    const int* __restrict__ offs,
    const float* __restrict__ wT,    // [T][200][32]
    const float* __restrict__ wxT,   // [T][50][16]
    const float* __restrict__ postB, // [50]
    const float* __restrict__ avg_accum, float* __restrict__ yT) {
    __shared__ float dp[3][64][33];
    __shared__ float xs[64][11];
    int t = blockIdx.x / NGRP3;
    int grp = blockIdx.x - t * NGRP3;
    int tid = threadIdx.x;
    int qd = tid >> 6, ln = tid & 63;
    int qdu = __builtin_amdgcn_readfirstlane(qd);
    int n = grp * 64 + ln;

    float acc[30];
#pragma unroll
    for (int i = 0; i < 30; ++i) acc[i] = 0.f;
    const __half* aggcol = aggT + (size_t)(t * 200) * NNP + n;
    const float4* wv = (const float4*)(wT + t * 200 * 32);
    int j0 = qdu * 50;
    for (int b = 0; b < 5; ++b) {
        float av[10];
#pragma unroll
        for (int k = 0; k < 10; ++k)
            av[k] = __half2float(aggcol[(size_t)(j0 + b * 10 + k) * NNP]);
#pragma unroll
        for (int k = 0; k < 10; ++k) {
            int j = j0 + b * 10 + k;
            float a = av[k];
            float4 w0 = wv[j * 8 + 0], w1 = wv[j * 8 + 1], w2 = wv[j * 8 + 2],
                   w3 = wv[j * 8 + 3], w4 = wv[j * 8 + 4], w5 = wv[j * 8 + 5],
                   w6 = wv[j * 8 + 6], w7 = wv[j * 8 + 7];
            acc[0] = fmaf(a, w0.x, acc[0]);   acc[1] = fmaf(a, w0.y, acc[1]);
            acc[2] = fmaf(a, w0.z, acc[2]);   acc[3] = fmaf(a, w0.w, acc[3]);
            acc[4] = fmaf(a, w1.x, acc[4]);   acc[5] = fmaf(a, w1.y, acc[5]);
            acc[6] = fmaf(a, w1.z, acc[6]);   acc[7] = fmaf(a, w1.w, acc[7]);
            acc[8] = fmaf(a, w2.x, acc[8]);   acc[9] = fmaf(a, w2.y, acc[9]);
            acc[10] = fmaf(a, w2.z, acc[10]); acc[11] = fmaf(a, w2.w, acc[11]);
            acc[12] = fmaf(a, w3.x, acc[12]); acc[13] = fmaf(a, w3.y, acc[13]);
            acc[14] = fmaf(a, w3.z, acc[14]); acc[15] = fmaf(a, w3.w, acc[15]);
            acc[16] = fmaf(a, w4.x, acc[16]); acc[17] = fmaf(a, w4.y, acc[17]);
            acc[18] = fmaf(a, w4.z, acc[18]); acc[19] = fmaf(a, w4.w, acc[19]);
            acc[20] = fmaf(a, w5.x, acc[20]); acc[21] = fmaf(a, w5.y, acc[21]);
            acc[22] = fmaf(a, w5.z, acc[22]); acc[23] = fmaf(a, w5.w, acc[23]);
            acc[24] = fmaf(a, w6.x, acc[24]); acc[25] = fmaf(a, w6.y, acc[25]);
            acc[26] = fmaf(a, w6.z, acc[26]); acc[27] = fmaf(a, w6.w, acc[27]);
            acc[28] = fmaf(a, w7.x, acc[28]); acc[29] = fmaf(a, w7.y, acc[29]);
        }
    }
    if (qdu == 1) {                 // x-part on wave 1, batched
        float xacc[10];
#pragma unroll
        for (int i = 0; i < 10; ++i) xacc[i] = 0.f;
        const float4* wxv = (const float4*)(wxT + t * 50 * 16);
        for (int b = 0; b < 5; ++b) {
            float av[10];
#pragma unroll
            for (int k = 0; k < 10; ++k)
                av[k] = hT[(size_t)(b * 10 + k) * NNP + n];
#pragma unroll
            for (int k = 0; k < 10; ++k) {
                int j = b * 10 + k;
                float a = av[k];
                float4 x0 = wxv[j * 4 + 0], x1 = wxv[j * 4 + 1], x2 = wxv[j * 4 + 2];
                xacc[0] = fmaf(a, x0.x, xacc[0]); xacc[1] = fmaf(a, x0.y, xacc[1]);
                xacc[2] = fmaf(a, x0.z, xacc[2]); xacc[3] = fmaf(a, x0.w, xacc[3]);
                xacc[4] = fmaf(a, x1.x, xacc[4]); xacc[5] = fmaf(a, x1.y, xacc[5]);
                xacc[6] = fmaf(a, x1.z, xacc[6]); xacc[7] = fmaf(a, x1.w, xacc[7]);
                xacc[8] = fmaf(a, x2.x, xacc[8]); xacc[9] = fmaf(a, x2.y, xacc[9]);
            }
        }
#pragma unroll
        for (int g = 0; g < 10; ++g) xs[ln][g] = xacc[g];
    }
    if (qdu != 0) {
#pragma unroll
        for (int g = 0; g < 30; ++g) dp[qdu - 1][ln][g] = acc[g];
    }
    __syncthreads();
    if (qd == 0 && n < NN) {
        int dgn = offs[n + 1] - offs[n];
        float cnt = (float)max(dgn, 1);
        float sc = logf(cnt + 1.0f) / (avg_accum[0] * (1.0f / NN));
        float isc = 1.0f / sc;
#pragma unroll
        for (int g = 0; g < 10; ++g) {
            float a0 = acc[g]      + dp[0][ln][g]      + dp[1][ln][g]      + dp[2][ln][g];
            float a1 = acc[10 + g] + dp[0][ln][10 + g] + dp[1][ln][10 + g] + dp[2][ln][10 + g];
            float a2 = acc[20 + g] + dp[0][ln][20 + g] + dp[1][ln][20 + g] + dp[2][ln][20 + g];
            yT[(size_t)(t * FOUT + g) * NNP + n] =
                postB[t * FOUT + g] + xs[ln][g] + a0 + sc * a1 + isc * a2;
        }
    }
}

// 50x50 linear + BN partial stats. 316 blocks x 256 thr.
__global__ __launch_bounds__(256) void k_lin(
    const float* __restrict__ yT, const float* __restrict__ linW,
    const float* __restrict__ linB, float* __restrict__ hrawT,
    float* __restrict__ part) {
    __shared__ float yl[64][51];
    __shared__ float bs[100];
    int tid = threadIdx.x;
    int n0 = blockIdx.x * 64;
    for (int idx = tid; idx < 64 * 50; idx += 256) {
        int q = idx >> 6, nl = idx & 63;
        yl[nl][q] = yT[(size_t)q * NNP + n0 + nl];
    }
    __syncthreads();
    int w = tid >> 6, nl = tid & 63;
    int wu = __builtin_amdgcn_readfirstlane(w);
    int n = n0 + nl;
    bool ok = n < NN;
    int c0 = wu * 13, c1 = min(50, c0 + 13);
    for (int c = c0; c < c1; ++c) {
        const float* wr = linW + c * 50;
        float a = linB[c];
#pragma unroll
        for (int q = 0; q < 50; ++q) a = fmaf(wr[q], yl[nl][q], a);
        hrawT[(size_t)c * NNP + n] = a;
        float s = ok ? a : 0.f;
        float sq = s * s;
#pragma unroll
        for (int o = 32; o > 0; o >>= 1) {
            s += __shfl_down(s, o);
            sq += __shfl_down(sq, o);
        }
        if (nl == 0) { bs[c] = s; bs[50 + c] = sq; }
    }
    __syncthreads();
    if (tid < 100) part[blockIdx.x * 100 + tid] = bs[tid];
}

// reduce part[316][100] -> bn[100].
__global__ __launch_bounds__(256) void k_bnred(const float* __restrict__ part,
                                               float* __restrict__ bn) {
    int c = blockIdx.x;
    int tid = threadIdx.x;
    float s = 0.f;
    for (int b = tid; b < NGRP3; b += 256) s += part[b * 100 + c];
    for (int o = 32; o > 0; o >>= 1) s += __shfl_down(s, o);
    __shared__ float ws[4];
    int lane = tid & 63, w = tid >> 6;
    if (lane == 0) ws[w] = s;
    __syncthreads();
    if (tid == 0) bn[c] = ws[0] + ws[1] + ws[2] + ws[3];
}

__global__ void k_bnapply(const float* __restrict__ hrawT, const float* __restrict__ bn,
                          const float* __restrict__ gamma, const float* __restrict__ beta,
                          float* __restrict__ hT) {
    int idx = blockIdx.x * 256 + threadIdx.x;
    if (idx < D * NNP) {
        int c = idx / NNP, n = idx % NNP;
        float mean = bn[c] * (1.0f / NN);
        float var = bn[50 + c] * (1.0f / NN) - mean * mean;
        float v = gamma[c] * (hrawT[idx] - mean) * rsqrtf(var + EPS) + beta[c];
        hT[idx] = (n < NN) ? fmaxf(v, 0.f) : 0.f;
    }
}

__global__ void k_mlp(const float* __restrict__ hT, const int* __restrict__ perm,
                      const float* __restrict__ W1, const float* __restrict__ b1,
                      const float* __restrict__ W2, const float* __restrict__ b2,
                      float* __restrict__ out) {
    int n = blockIdx.x * 256 + threadIdx.x;
    if (n >= NN) return;
    float hv[50];
#pragma unroll
    for (int f = 0; f < 50; ++f) hv[f] = hT[(size_t)f * NNP + n];
    float s = b2[0];
    for (int o = 0; o < 25; ++o) {
        float a = b1[o];
        const float* w = W1 + o * 50;
#pragma unroll
        for (int f = 0; f < 50; ++f) a += w[f] * hv[f];
        s += W2[o] * fmaxf(a, 0.f);
    }
    out[perm[n]] = 1.0f / (1.0f + expf(-s));
}

// ------------------------------------------------------------------ launch
extern "C" void kernel_launch(void* const* d_in, const int* in_sizes, int n_in,
                              void* d_out, int out_size, void* d_ws, size_t ws_size,
                              hipStream_t stream) {
    const int* x = (const int*)d_in[0];
    const int* ei = (const int*)d_in[1];
    const int* src = ei;
    const int* dst = ei + NE;
    const float* emb   = (const float*)d_in[4];
    const float* preW  = (const float*)d_in[5];
    const float* preB  = (const float*)d_in[6];
    const float* postW = (const float*)d_in[7];
    const float* postB = (const float*)d_in[8];
    const float* linW  = (const float*)d_in[9];
    const float* linB  = (const float*)d_in[10];
    const float* gamma = (const float*)d_in[11];
    const float* beta  = (const float*)d_in[12];
    const float* W1 = (const float*)d_in[13];
    const float* b1 = (const float*)d_in[14];
    const float* W2 = (const float*)d_in[15];
    const float* b2 = (const float*)d_in[16];
    float* outp = (float*)d_out;

    char* wsp = (char*)d_ws;
    size_t off = 0;
    auto alloc = [&](size_t bytes) {
        void* p = wsp + off;
        off = (off + bytes + 1023) & ~(size_t)1023;
        return p;
    };
    int* deg     = (int*)alloc(NN * 4);
    int* cursor  = (int*)alloc(NN * 4);
    int* offs    = (int*)alloc((NN + 1) * 4);
    int* csr     = (int*)alloc(NE * 4);
    int* perm    = (int*)alloc(NN * 4);
    int* invp    = (int*)alloc(NN * 4);
    int* hist    = (int*)alloc(256 * 4);
    int* binbase = (int*)alloc(256 * 4);
    int* ebase   = (int*)alloc(256 * 4);
    int* cursorb = (int*)alloc(256 * 4);
    float* bn    = (float*)alloc(512);     // [0:100) BN stats, [100] avg_log
    float* part  = (float*)alloc((size_t)NGRP3 * 100 * 4);
    float* hT    = (float*)alloc((size_t)D * NNP * 4);
    float* hrawT = (float*)alloc((size_t)D * NNP * 4);
    float* yT    = (float*)alloc((size_t)D * NNP * 4);
    __half* aih  = (__half*)alloc((size_t)NN * ASTR * 2);
    __half* ajh  = (__half*)alloc((size_t)NN * ASTR * 2);
    float* wT    = (float*)alloc((size_t)4 * TOWERS * 200 * 32 * 4);
    float* wxT   = (float*)alloc((size_t)4 * TOWERS * 50 * 16 * 4);
    __half* aggT = (__half*)alloc((size_t)1000 * NNP * 2);  // fp16 stats+base
    (void)ws_size; (void)in_sizes; (void)n_in; (void)out_size;

    hipMemsetAsync(deg, 0, NN * 4, stream);
    hipMemsetAsync(cursor, 0, NN * 4, stream);
    hipMemsetAsync(hist, 0, 256 * 4, stream);
    hipMemsetAsync(cursorb, 0, 256 * 4, stream);
    hipMemsetAsync(bn, 0, 512, stream);

    k_deg<<<(NE + 255) / 256, 256, 0, stream>>>(dst, deg);
    k_hist<<<(NN + 255) / 256, 256, 0, stream>>>(deg, hist);
    k_binscan<<<1, 256, 0, stream>>>(hist, binbase, ebase, bn + 100);
    k_scatter<<<(NN + 255) / 256, 256, 0, stream>>>(deg, binbase, ebase, cursorb,
                                                    perm, invp, offs);
    k_csr<<<(NE + 255) / 256, 256, 0, stream>>>(src, dst, offs, invp, cursor, csr);
    k_emb<<<(D * NNP + 255) / 256, 256, 0, stream>>>(x, emb, perm, hT);
    k_wt<<<(4 * TOWERS * 200 * 32 + 4 * TOWERS * 50 * 16 + 255) / 256, 256, 0, stream>>>(postW, wT, wxT);

    int aggblocks = 313 * 4;
    for (int l = 0; l < 4; ++l) {
        k_pre<<<NN / PRE_NT, 512, 0, stream>>>(hT, preW + l * TD * 100, aih, ajh);
        k_agg<<<aggblocks, 512, 0, stream>>>(ajh, offs, csr, aih, preB + l * TD, aggT);
        k_post<<<NGRP3 * TOWERS, 256, 0, stream>>>(hT, aggT, offs,
                                                   wT + l * TOWERS * 200 * 32,
                                                   wxT + l * TOWERS * 50 * 16,
                                                   postB + l * 50, bn + 100, yT);
        k_lin<<<NGRP3, 256, 0, stream>>>(yT, linW + l * 2500, linB + l * 50, hrawT, part);
        k_bnred<<<100, 256, 0, stream>>>(part, bn);
        k_bnapply<<<(D * NNP + 255) / 256, 256, 0, stream>>>(hrawT, bn, gamma + l * 50,
                                                             beta + l * 50, hT);
    }
    k_mlp<<<(NN + 255) / 256, 256, 0, stream>>>(hT, perm, W1, b1, W2, b2, outp);
}